// Round 1
// baseline (291.304 us; speedup 1.0000x reference)
//
#include <hip/hip_runtime.h>
#include <hip/hip_fp16.h>

#define NFEAT 64
#define NBINS 255
#define NPAIRS 32
#define BATCH 262144
#define BIGF 3.0e38f

// ws layout (floats):
//   [0      , 16384) : E_pad  [64][256] fp32 (edges padded, row stride 256, last = BIGF)
//   [16384  , 32768) : PE_pad [64][256] fp32 (pair_edges padded)
//   [32768  , 36864) : midE   [64][64]  fp32 (every 4th edge: e[4k+3], k=63 -> BIGF)
//   [36864  , 40960) : midPE  [64][64]  fp32
//   [40960  , 49152) : W16    [64][256] fp16 (as 8192 dwords)
// total 196608 bytes

__global__ void ebm_prep(const float* __restrict__ edges,
                         const float* __restrict__ pair_edges,
                         const float* __restrict__ w,
                         float* __restrict__ ws) {
    int tid = blockIdx.x * blockDim.x + threadIdx.x;  // 16384 threads
    float* E   = ws;
    float* PE  = ws + 16384;
    float* mE  = ws + 32768;
    float* mPE = ws + 36864;
    __half* W  = (__half*)(ws + 40960);
    if (tid < 16384) {
        int f = tid >> 8, j = tid & 255;
        E[tid]  = (j < NBINS) ? edges[f * NBINS + j]      : BIGF;
        PE[tid] = (j < NBINS) ? pair_edges[f * NBINS + j] : BIGF;
        W[tid]  = __float2half(w[tid]);
        if (tid < 4096) {
            int ff = tid >> 6, k = tid & 63;
            mE[tid]  = (k < 63) ? edges[ff * NBINS + 4 * k + 3]      : BIGF;
            mPE[tid] = (k < 63) ? pair_edges[ff * NBINS + 4 * k + 3] : BIGF;
        }
    }
}

__global__ __launch_bounds__(512, 4) void ebm_main(
    const float* __restrict__ x,
    const int*   __restrict__ pairs,
    const float* __restrict__ tables,
    const float* __restrict__ bias,
    const float* __restrict__ ws,
    float*       __restrict__ out) {

    __shared__ float  sMidE[4096];   // 16 KB
    __shared__ float  sMidPE[4096];  // 16 KB
    __shared__ __half sW[16384];     // 32 KB

    const float* E   = ws;
    const float* PE  = ws + 16384;
    const float* mE  = ws + 32768;
    const float* mPE = ws + 36864;
    const unsigned int* W32 = (const unsigned int*)(ws + 40960);

    int tid = threadIdx.x;
    for (int i = tid; i < 4096; i += 512) { sMidE[i] = mE[i]; sMidPE[i] = mPE[i]; }
    unsigned int* sW32 = (unsigned int*)sW;
    for (int i = tid; i < 8192; i += 512) sW32[i] = W32[i];
    __syncthreads();

    int lane = tid & 63;
    int wave = tid >> 6;
    int gw = blockIdx.x * 8 + wave;        // grid = 512 blocks * 8 waves = 4096 waves
    // each wave handles 64 contiguous rows: 4096 * 64 = 262144

    // level-0 coarse edges in registers: positions 16j+15 (j=0..14) -> range-16 bucket
    float cu[15], cp[15];
#pragma unroll
    for (int j = 0; j < 15; ++j) {
        cu[j] = E[lane * 256 + 16 * j + 15];
        cp[j] = PE[lane * 256 + 16 * j + 15];
    }

    int pa = 0, pb = 0;
    if (lane < NPAIRS) { pa = pairs[2 * lane]; pb = pairs[2 * lane + 1]; }
    // is this lane's feature referenced by any pair?
    bool act = false;
#pragma unroll 1
    for (int k = 0; k < 2 * NPAIRS; ++k) act = act || (pairs[k] == lane);

    float bias0 = bias[0];

    const float4* E4      = (const float4*)E;
    const float4* PE4     = (const float4*)PE;
    const float4* sMidE4  = (const float4*)sMidE;
    const float4* sMidPE4 = (const float4*)sMidPE;

    int row0 = gw * 64;
    for (int r = 0; r < 64; ++r) {
        int row = row0 + r;
        float xv = x[row * 64 + lane];   // coalesced 256B per wave

        // ---- unary search: count c = #{edges[f][i] <= xv} ----
        int t = 0;
#pragma unroll
        for (int j = 0; j < 15; ++j) t += (xv >= cu[j]);
        float4 mv = sMidE4[lane * 16 + t];                    // mids 4t..4t+3
        int m = (xv >= mv.x) + (xv >= mv.y) + (xv >= mv.z);   // range 16 -> 4
        int lo = t * 16 + m * 4;
        float4 fv = E4[lane * 64 + (lo >> 2)];                // aligned 16B window
        int c = lo + (xv >= fv.x) + (xv >= fv.y) + (xv >= fv.z);
        int bin = (c < NBINS) ? c + 1 : 0;
        float s = __half2float(sW[lane * 256 + bin]);

        // ---- pair search (only for features appearing in pairs) ----
        int pidx = 0;
        if (act) {
            int t2 = 0;
#pragma unroll
            for (int j = 0; j < 15; ++j) t2 += (xv >= cp[j]);
            float4 mv2 = sMidPE4[lane * 16 + t2];
            int m2 = (xv >= mv2.x) + (xv >= mv2.y) + (xv >= mv2.z);
            int lo2 = t2 * 16 + m2 * 4;
            float4 fv2 = PE4[lane * 64 + (lo2 >> 2)];
            int c2 = lo2 + (xv >= fv2.x) + (xv >= fv2.y) + (xv >= fv2.z);
            pidx = (c2 < NBINS) ? c2 + 1 : 0;
        }

        // exchange bins to pair lanes
        int li = __shfl(pidx, pa, 64);
        int ri = __shfl(pidx, pb, 64);
        if (lane < NPAIRS) {
            s += tables[(lane << 16) + (li << 8) + ri];
        }

        // wave-64 reduction
#pragma unroll
        for (int o = 32; o > 0; o >>= 1) s += __shfl_xor(s, o, 64);

        if (lane == 0) {
            out[row] = 1.0f / (1.0f + __expf(-(s + bias0)));
        }
    }
}

extern "C" void kernel_launch(void* const* d_in, const int* in_sizes, int n_in,
                              void* d_out, int out_size, void* d_ws, size_t ws_size,
                              hipStream_t stream) {
    const float* x          = (const float*)d_in[0];
    const float* edges      = (const float*)d_in[1];
    const float* w          = (const float*)d_in[2];
    const float* pair_edges = (const float*)d_in[3];
    const int*   pairs      = (const int*)d_in[4];
    const float* tables     = (const float*)d_in[5];
    const float* bias       = (const float*)d_in[6];
    float* out = (float*)d_out;
    float* ws  = (float*)d_ws;

    ebm_prep<<<64, 256, 0, stream>>>(edges, pair_edges, w, ws);
    ebm_main<<<512, 512, 0, stream>>>(x, pairs, tables, bias, ws, out);
}

// Round 2
// 273.810 us; speedup vs baseline: 1.0639x; 1.0639x over previous
//
#include <hip/hip_runtime.h>
#include <hip/hip_fp16.h>

#define NFEAT 64
#define NBINS 255
#define NPAIRS 32
#define BATCH 262144
#define BIGF 3.0e38f

// ws layout (floats):
//   [0      , 16384) : E_pad  [64][256] fp32 (edges padded, row stride 256, tail = BIGF)
//   [16384  , 32768) : PE_pad [64][256] fp32
//   [32768  , 36864) : midE   [64][64]  fp32 (every 4th edge e[4k+3], tail = BIGF)
//   [36864  , 40960) : midPE  [64][64]  fp32
//   [40960  , 49152) : W16    [64][256] fp16
// total 196608 bytes

__global__ void ebm_prep(const float* __restrict__ edges,
                         const float* __restrict__ pair_edges,
                         const float* __restrict__ w,
                         float* __restrict__ ws) {
    int tid = blockIdx.x * blockDim.x + threadIdx.x;  // 16384 threads
    float* E   = ws;
    float* PE  = ws + 16384;
    float* mE  = ws + 32768;
    float* mPE = ws + 36864;
    __half* W  = (__half*)(ws + 40960);
    if (tid < 16384) {
        int f = tid >> 8, j = tid & 255;
        E[tid]  = (j < NBINS) ? edges[f * NBINS + j]      : BIGF;
        PE[tid] = (j < NBINS) ? pair_edges[f * NBINS + j] : BIGF;
        W[tid]  = __float2half(w[tid]);
        if (tid < 4096) {
            int ff = tid >> 6, k = tid & 63;
            mE[tid]  = (k < 63) ? edges[ff * NBINS + 4 * k + 3]      : BIGF;
            mPE[tid] = (k < 63) ? pair_edges[ff * NBINS + 4 * k + 3] : BIGF;
        }
    }
}

// merge two per-lane partial streams across xor-partner lanes:
// lanes with (lane&mask)==0 end up carrying a's stream, others b's.
__device__ __forceinline__ float merge2(float a, float b, int mask, int lane) {
    bool lo = (lane & mask) == 0;
    float send = lo ? b : a;
    float recv = __shfl_xor(send, mask, 64);
    float keep = lo ? a : b;
    return keep + recv;
}

__global__ __launch_bounds__(512, 4) void ebm_main(
    const float* __restrict__ x,
    const int*   __restrict__ pairs,
    const float* __restrict__ tables,
    const float* __restrict__ bias,
    const float* __restrict__ ws,
    float*       __restrict__ out) {

    __shared__ float4 sMidE[1024];   // [64][16] float4, xor-swizzled by (f&15)
    __shared__ float4 sMidPE[1024];
    __shared__ __half sW[16384];     // 32 KB

    const float* E   = ws;
    const float* PE  = ws + 16384;
    const float* mE  = ws + 32768;
    const float* mPE = ws + 36864;
    const unsigned int* W32 = (const unsigned int*)(ws + 40960);

    int tid = threadIdx.x;
    // stage mids with xor-swizzle: physical float4 slot j' = j ^ (f&15)
    {
        float* dE  = (float*)sMidE;
        float* dPE = (float*)sMidPE;
        for (int i = tid; i < 4096; i += 512) {
            int f = i >> 6, k = i & 63;
            int j = k >> 2, e = k & 3;
            int js = j ^ (f & 15);
            dE[f * 64 + js * 4 + e]  = mE[i];
            dPE[f * 64 + js * 4 + e] = mPE[i];
        }
        unsigned int* sW32 = (unsigned int*)sW;
        for (int i = tid; i < 8192; i += 512) sW32[i] = W32[i];
    }
    __syncthreads();

    int lane = tid & 63;
    int wave = tid >> 6;
    int gw = blockIdx.x * 8 + wave;      // 512 blocks * 8 waves = 4096 waves
    int swz = lane & 15;

    // level-0 coarse edges in registers (positions 16j+15) -> range-16 bucket
    float cu[15], cp[15];
#pragma unroll
    for (int j = 0; j < 15; ++j) {
        cu[j] = E[lane * 256 + 16 * j + 15];
        cp[j] = PE[lane * 256 + 16 * j + 15];
    }

    int pa = 0, pb = 0;
    if (lane < NPAIRS) { pa = pairs[2 * lane]; pb = pairs[2 * lane + 1]; }
    bool act = false;
#pragma unroll 1
    for (int k = 0; k < 2 * NPAIRS; ++k) act = act || (pairs[k] == lane);

    float bias0 = bias[0];

    const float4* E4  = (const float4*)E;
    const float4* PE4 = (const float4*)PE;

    int row0 = gw * 64;

    // prefetch first 4 rows
    float xv[4];
#pragma unroll
    for (int u = 0; u < 4; ++u) xv[u] = x[(row0 + u) * 64 + lane];

#pragma unroll 1
    for (int it = 0; it < 16; ++it) {
        int rowbase = row0 + it * 4;

        // prefetch next iteration's x (guard last iter: reload current rows)
        float xn[4];
        int nb = (it < 15) ? (rowbase + 4) : rowbase;
#pragma unroll
        for (int u = 0; u < 4; ++u) xn[u] = x[(nb + u) * 64 + lane];

        // ---- phase 1: unary coarse (VALU) ----
        int t[4];
#pragma unroll
        for (int u = 0; u < 4; ++u) {
            int tt = 0;
#pragma unroll
            for (int j = 0; j < 15; ++j) tt += (xv[u] >= cu[j]);
            t[u] = tt;
        }
        // ---- phase 2: unary mid LDS loads (4 independent) ----
        float4 mv[4];
#pragma unroll
        for (int u = 0; u < 4; ++u) mv[u] = sMidE[lane * 16 + (t[u] ^ swz)];

        // ---- phase 3: pair coarse (VALU, overlaps LDS latency) ----
        int t2[4] = {0, 0, 0, 0};
        if (act) {
#pragma unroll
            for (int u = 0; u < 4; ++u) {
                int tt = 0;
#pragma unroll
                for (int j = 0; j < 15; ++j) tt += (xv[u] >= cp[j]);
                t2[u] = tt;
            }
        }

        // ---- phase 4: consume unary mids, launch unary fine (4 global) ----
        int lo[4];
        float4 fv[4];
#pragma unroll
        for (int u = 0; u < 4; ++u) {
            int m = (xv[u] >= mv[u].x) + (xv[u] >= mv[u].y) + (xv[u] >= mv[u].z);
            lo[u] = t[u] * 16 + m * 4;
            fv[u] = E4[lane * 64 + (lo[u] >> 2)];
        }

        // ---- phase 5: pair mids (4 LDS) ----
        float4 mv2[4];
#pragma unroll
        for (int u = 0; u < 4; ++u) mv2[u] = sMidPE[lane * 16 + (t2[u] ^ swz)];

        // ---- phase 6: consume pair mids, launch pair fine (4 global) ----
        int lo2[4];
        float4 fv2[4];
#pragma unroll
        for (int u = 0; u < 4; ++u) {
            int m2 = (xv[u] >= mv2[u].x) + (xv[u] >= mv2[u].y) + (xv[u] >= mv2[u].z);
            lo2[u] = t2[u] * 16 + m2 * 4;
            fv2[u] = PE4[lane * 64 + (lo2[u] >> 2)];
        }

        // ---- phase 7: consume unary fine -> bins, launch sW loads ----
        float wv[4];
#pragma unroll
        for (int u = 0; u < 4; ++u) {
            int c = lo[u] + (xv[u] >= fv[u].x) + (xv[u] >= fv[u].y) + (xv[u] >= fv[u].z);
            int bin = (c < NBINS) ? c + 1 : 0;
            wv[u] = __half2float(sW[lane * 256 + bin]);
        }

        // ---- phase 8: consume pair fine -> pidx, exchange, table gathers ----
        int pidx[4];
#pragma unroll
        for (int u = 0; u < 4; ++u) {
            int c2 = lo2[u] + (xv[u] >= fv2[u].x) + (xv[u] >= fv2[u].y) + (xv[u] >= fv2[u].z);
            pidx[u] = (c2 < NBINS) ? c2 + 1 : 0;
        }
        float tvl[4] = {0.f, 0.f, 0.f, 0.f};
#pragma unroll
        for (int u = 0; u < 4; ++u) {
            int li = __shfl(pidx[u], pa, 64);
            int ri = __shfl(pidx[u], pb, 64);
            if (lane < NPAIRS) tvl[u] = tables[(lane << 16) + (li << 8) + ri];
        }

        // ---- phase 9: per-lane sums, 7-shuffle 4-row reduction ----
        float s0 = wv[0] + tvl[0];
        float s1 = wv[1] + tvl[1];
        float s2 = wv[2] + tvl[2];
        float s3 = wv[3] + tvl[3];

        float m01 = merge2(s0, s1, 1, lane);
        float m23 = merge2(s2, s3, 1, lane);
        float q   = merge2(m01, m23, 2, lane);
#pragma unroll
        for (int o = 4; o <= 32; o <<= 1) q += __shfl_xor(q, o, 64);

        if (lane < 4) {
            out[rowbase + lane] = 1.0f / (1.0f + __expf(-(q + bias0)));
        }

        xv[0] = xn[0]; xv[1] = xn[1]; xv[2] = xn[2]; xv[3] = xn[3];
    }
}

extern "C" void kernel_launch(void* const* d_in, const int* in_sizes, int n_in,
                              void* d_out, int out_size, void* d_ws, size_t ws_size,
                              hipStream_t stream) {
    const float* x          = (const float*)d_in[0];
    const float* edges      = (const float*)d_in[1];
    const float* w          = (const float*)d_in[2];
    const float* pair_edges = (const float*)d_in[3];
    const int*   pairs      = (const int*)d_in[4];
    const float* tables     = (const float*)d_in[5];
    const float* bias       = (const float*)d_in[6];
    float* out = (float*)d_out;
    float* ws  = (float*)d_ws;

    ebm_prep<<<64, 256, 0, stream>>>(edges, pair_edges, w, ws);
    ebm_main<<<512, 512, 0, stream>>>(x, pairs, tables, bias, ws, out);
}

// Round 3
// 229.659 us; speedup vs baseline: 1.2684x; 1.1922x over previous
//
#include <hip/hip_runtime.h>
#include <hip/hip_fp16.h>

#define NFEAT 64
#define NBINS 255
#define NPAIRS 32
#define BATCH 262144
#define BIGF 3.0e38f

// ws layout (bytes):
//   [0      ,  65536) : E_pad  [64][256] fp32 (tail = BIGF)
//   [65536  , 131072) : PE_pad [64][256] fp32
//   [131072 , 163840) : W16    [64][256] fp16
//   [163840 ,4358144) : T16    [32][256][256] fp16 (only if ws_size allows)

__global__ void ebm_prep_edges(const float* __restrict__ edges,
                               const float* __restrict__ pair_edges,
                               const float* __restrict__ w,
                               float* __restrict__ ws) {
    int tid = blockIdx.x * blockDim.x + threadIdx.x;  // 16384 threads
    float* E   = ws;
    float* PE  = ws + 16384;
    __half* W  = (__half*)(ws + 32768);
    int f = tid >> 8, j = tid & 255;
    E[tid]  = (j < NBINS) ? edges[f * NBINS + j]      : BIGF;
    PE[tid] = (j < NBINS) ? pair_edges[f * NBINS + j] : BIGF;
    W[tid]  = __float2half(w[tid]);
}

__global__ void ebm_prep_tables(const float4* __restrict__ t4,
                                uint2* __restrict__ o2) {
    int i = blockIdx.x * blockDim.x + threadIdx.x;  // 524288 threads
    float4 v = t4[i];
    uint2 o;
    o.x = (unsigned int)__half_as_ushort(__float2half(v.x)) |
          ((unsigned int)__half_as_ushort(__float2half(v.y)) << 16);
    o.y = (unsigned int)__half_as_ushort(__float2half(v.z)) |
          ((unsigned int)__half_as_ushort(__float2half(v.w)) << 16);
    o2[i] = o;
}

// lanes with (lane&mask)==0 carry a's stream, others b's; result summed with partner
__device__ __forceinline__ float merge2(float a, float b, int mask, int lane) {
    bool lo = (lane & mask) == 0;
    float send = lo ? b : a;
    float recv = __shfl_xor(send, mask, 64);
    float keep = lo ? a : b;
    return keep + recv;
}

__global__ __launch_bounds__(1024, 4) void ebm_main(
    const float* __restrict__ x,
    const int*   __restrict__ pairs,
    const float* __restrict__ tables_f32,
    const float* __restrict__ bias,
    const float* __restrict__ ws,
    const __half* __restrict__ T16,
    int useT16,
    float*       __restrict__ out) {

    // exactly 160 KiB:
    __shared__ float  sE[16384];    // [64 feat][64 float4-slots], slot js = j ^ f
    __shared__ float  sPE[16384];
    __shared__ __half sW[16384];    // [64][256], dword-index xor-swizzled by (f&15)

    const float* E  = ws;
    const float* PE = ws + 16384;
    const unsigned int* W32 = (const unsigned int*)(ws + 32768);

    int tid  = threadIdx.x;
    int lane = tid & 63;            // lane == feature index f

    // ---- stage edges (swizzled) + W ----
    for (int i = tid; i < 16384; i += 1024) {
        int f = i >> 8, k = i & 255;
        int js = (((k >> 2) ^ f) << 2) + (k & 3);
        sE[f * 256 + js]  = E[i];
        sPE[f * 256 + js] = PE[i];
    }
    {
        unsigned int* sW32 = (unsigned int*)sW;
        for (int i = tid; i < 8192; i += 1024) {
            int f = i >> 7, kd = i & 127;
            sW32[f * 128 + (kd ^ (f & 15))] = W32[i];
        }
    }

    int pa = 0, pb = 0;
    if (lane < NPAIRS) { pa = pairs[2 * lane]; pb = pairs[2 * lane + 1]; }
    bool act = false;
#pragma unroll 1
    for (int k = 0; k < 2 * NPAIRS; ++k) act = act || (pairs[k] == lane);
    float bias0 = bias[0];

    __syncthreads();

    // ---- coarse edges (positions 8j+7, j=0..30) into registers, from LDS ----
    float cu[31], cp[31];
#pragma unroll
    for (int j = 0; j < 31; ++j) {
        int si = lane * 256 + (((2 * j + 1) ^ lane) << 2) + 3;
        cu[j] = sE[si];
        cp[j] = sPE[si];
    }

    const float4* sE4  = (const float4*)sE;
    const float4* sPE4 = (const float4*)sPE;
    int wswz = (lane & 15) << 1;

    int gw = blockIdx.x * 16 + (tid >> 6);   // 512 blocks * 16 waves = 8192 waves
    int row0 = gw * 32;                      // 32 rows per wave

    float xv[2];
#pragma unroll
    for (int u = 0; u < 2; ++u) xv[u] = x[(row0 + u) * 64 + lane];

#pragma unroll 1
    for (int it = 0; it < 16; ++it) {
        int rowbase = row0 + it * 2;

        // prefetch next 2 rows
        float xn[2];
        int nb = (it < 15) ? (rowbase + 2) : rowbase;
#pragma unroll
        for (int u = 0; u < 2; ++u) xn[u] = x[(nb + u) * 64 + lane];

        // ---- unary coarse (registers) -> range 8 ----
        int r[2];
#pragma unroll
        for (int u = 0; u < 2; ++u) {
            int t = 0;
#pragma unroll
            for (int j = 0; j < 31; ++j) t += (xv[u] >= cu[j]);
            r[u] = t;
        }
        // ---- unary fine: 2 swizzled b128 per row ----
        float4 a0[2], a1[2];
#pragma unroll
        for (int u = 0; u < 2; ++u) {
            a0[u] = sE4[lane * 64 + ((2 * r[u]) ^ lane)];
            a1[u] = sE4[lane * 64 + ((2 * r[u] + 1) ^ lane)];
        }

        // ---- pair coarse (overlaps LDS latency) ----
        int r2[2] = {0, 0};
        if (act) {
#pragma unroll
            for (int u = 0; u < 2; ++u) {
                int t = 0;
#pragma unroll
                for (int j = 0; j < 31; ++j) t += (xv[u] >= cp[j]);
                r2[u] = t;
            }
        }

        // ---- consume unary fine -> bin -> W gather ----
        float wv[2];
#pragma unroll
        for (int u = 0; u < 2; ++u) {
            int d = (xv[u] >= a0[u].x) + (xv[u] >= a0[u].y) +
                    (xv[u] >= a0[u].z) + (xv[u] >= a0[u].w) +
                    (xv[u] >= a1[u].x) + (xv[u] >= a1[u].y) + (xv[u] >= a1[u].z);
            int c = 8 * r[u] + d;
            int bin = (c < NBINS) ? c + 1 : 0;
            wv[u] = __half2float(sW[lane * 256 + (bin ^ wswz)]);
        }

        // ---- pair fine ----
        int pidx[2] = {0, 0};
        if (act) {
            float4 b0[2], b1[2];
#pragma unroll
            for (int u = 0; u < 2; ++u) {
                b0[u] = sPE4[lane * 64 + ((2 * r2[u]) ^ lane)];
                b1[u] = sPE4[lane * 64 + ((2 * r2[u] + 1) ^ lane)];
            }
#pragma unroll
            for (int u = 0; u < 2; ++u) {
                int d = (xv[u] >= b0[u].x) + (xv[u] >= b0[u].y) +
                        (xv[u] >= b0[u].z) + (xv[u] >= b0[u].w) +
                        (xv[u] >= b1[u].x) + (xv[u] >= b1[u].y) + (xv[u] >= b1[u].z);
                int c = 8 * r2[u] + d;
                pidx[u] = (c < NBINS) ? c + 1 : 0;
            }
        }

        // ---- packed exchange (2 rows per shuffle) + table gather ----
        int pk = pidx[0] | (pidx[1] << 16);
        int lk = __shfl(pk, pa, 64);
        int rk = __shfl(pk, pb, 64);
        float tv[2] = {0.f, 0.f};
        if (lane < NPAIRS) {
            int li0 = lk & 0xffff, ri0 = rk & 0xffff;
            int li1 = lk >> 16,    ri1 = rk >> 16;
            if (useT16) {
                tv[0] = __half2float(T16[(lane << 16) + (li0 << 8) + ri0]);
                tv[1] = __half2float(T16[(lane << 16) + (li1 << 8) + ri1]);
            } else {
                tv[0] = tables_f32[(lane << 16) + (li0 << 8) + ri0];
                tv[1] = tables_f32[(lane << 16) + (li1 << 8) + ri1];
            }
        }

        // ---- reduce 2 rows in 6 shuffles ----
        float s0 = wv[0] + tv[0];
        float s1 = wv[1] + tv[1];
        float q = merge2(s0, s1, 1, lane);
#pragma unroll
        for (int o = 2; o <= 32; o <<= 1) q += __shfl_xor(q, o, 64);

        if (lane < 2) {
            out[rowbase + lane] = 1.0f / (1.0f + __expf(-(q + bias0)));
        }

        xv[0] = xn[0]; xv[1] = xn[1];
    }
}

extern "C" void kernel_launch(void* const* d_in, const int* in_sizes, int n_in,
                              void* d_out, int out_size, void* d_ws, size_t ws_size,
                              hipStream_t stream) {
    const float* x          = (const float*)d_in[0];
    const float* edges      = (const float*)d_in[1];
    const float* w          = (const float*)d_in[2];
    const float* pair_edges = (const float*)d_in[3];
    const int*   pairs      = (const int*)d_in[4];
    const float* tables     = (const float*)d_in[5];
    const float* bias       = (const float*)d_in[6];
    float* out = (float*)d_out;
    float* ws  = (float*)d_ws;

    int useT16 = (ws_size >= (size_t)4358144) ? 1 : 0;
    __half* T16 = (__half*)((char*)d_ws + 163840);

    ebm_prep_edges<<<64, 256, 0, stream>>>(edges, pair_edges, w, ws);
    if (useT16) {
        ebm_prep_tables<<<512, 1024, 0, stream>>>((const float4*)tables, (uint2*)T16);
    }
    ebm_main<<<512, 1024, 0, stream>>>(x, pairs, tables, bias, ws, T16, useT16, out);
}

// Round 4
// 216.229 us; speedup vs baseline: 1.3472x; 1.0621x over previous
//
#include <hip/hip_runtime.h>
#include <hip/hip_fp16.h>

#define NBINS 255
#define NPAIRS 32
#define BIGF 3.0e38f

// ws layout (bytes):
//   [0      ,  65536) : E   [64][256] fp32 natural (tail = BIGF)
//   [65536  , 131072) : PE  [64][256] fp32 natural
//   [131072 , 163840) : W16 [64][256] fp16, PRE-SHIFTED: W16[f][c] = w[f][c<255?c+1:0]
//   [163840 ,4358144) : T16 [32][256][256] fp16, PRE-SHIFTED both dims (if ws allows)

__global__ void ebm_prep_edges(const float* __restrict__ edges,
                               const float* __restrict__ pair_edges,
                               const float* __restrict__ w,
                               float* __restrict__ ws) {
    int tid = blockIdx.x * blockDim.x + threadIdx.x;  // 16384 threads
    float* E   = ws;
    float* PE  = ws + 16384;
    __half* W  = (__half*)(ws + 32768);
    int f = tid >> 8, j = tid & 255;
    E[tid]  = (j < NBINS) ? edges[f * NBINS + j]      : BIGF;
    PE[tid] = (j < NBINS) ? pair_edges[f * NBINS + j] : BIGF;
    int src = (j < 255) ? j + 1 : 0;                  // pre-shifted bin remap
    W[tid]  = __float2half(w[f * 256 + src]);
}

__global__ void ebm_prep_tables(const float* __restrict__ tables,
                                unsigned short* __restrict__ o) {
    int i = blockIdx.x * blockDim.x + threadIdx.x;    // 2097152 threads
    int b = i & 255, a = (i >> 8) & 255, p = i >> 16;
    int ra = (a < 255) ? a + 1 : 0;
    int rb = (b < 255) ? b + 1 : 0;
    float v = tables[(p << 16) + (ra << 8) + rb];
    o[i] = __half_as_ushort(__float2half(v));
}

// lanes with (lane&mask)==0 carry a's stream, others b's; summed with partner
__device__ __forceinline__ float merge2(float a, float b, int mask, int lane) {
    bool lo = (lane & mask) == 0;
    float send = lo ? b : a;
    float recv = __shfl_xor(send, mask, 64);
    float keep = lo ? a : b;
    return keep + recv;
}

__global__ __launch_bounds__(1024, 4) void ebm_main(
    const float* __restrict__ x,
    const int*   __restrict__ pairs,
    const float* __restrict__ tables_f32,
    const float* __restrict__ bias,
    const float* __restrict__ ws,
    const __half* __restrict__ T16,
    int useT16,
    float*       __restrict__ out) {

    // 160 KiB total; edge arrays full-float xor-swizzled: phys index = k ^ f
    __shared__ float  sE[16384];
    __shared__ float  sPE[16384];
    __shared__ __half sW[16384];   // natural, pre-shifted values

    const float* E  = ws;
    const float* PE = ws + 16384;
    const unsigned int* W32 = (const unsigned int*)(ws + 32768);

    int tid  = threadIdx.x;
    int lane = tid & 63;           // lane == feature f

    for (int i = tid; i < 16384; i += 1024) {
        int f = i >> 8, k = i & 255;
        sE[(f << 8) + (k ^ f)]  = E[i];
        sPE[(f << 8) + (k ^ f)] = PE[i];
    }
    {
        unsigned int* sW32 = (unsigned int*)sW;
        for (int i = tid; i < 8192; i += 1024) sW32[i] = W32[i];
    }

    // coarse edges (positions 16j+15, j=0..14) from ws natural arrays
    float cu[15], cp[15];
#pragma unroll
    for (int j = 0; j < 15; ++j) {
        cu[j] = E[lane * 256 + 16 * j + 15];
        cp[j] = PE[lane * 256 + 16 * j + 15];
    }

    int pa = 0, pb = 0;
    if (lane < NPAIRS) { pa = pairs[2 * lane]; pb = pairs[2 * lane + 1]; }
    bool act = false;
#pragma unroll 1
    for (int k = 0; k < 2 * NPAIRS; ++k) act = act || (pairs[k] == lane);
    float bias0 = bias[0];

    __syncthreads();

    // per-lane swizzle constants
    const int fbase = lane << 8;          // float index of feature row
    const int fh    = lane & 48;          // xor for mid high nibble
    const int ci0   = 3  ^ (lane & 15);   // mid element offsets (low nibble)
    const int ci1   = 7  ^ (lane & 15);
    const int ci2   = 11 ^ (lane & 15);
    const int fq    = lane >> 2;          // xor for fine float4 slot (0..15)

    const float4* sE4  = (const float4*)sE;
    const float4* sPE4 = (const float4*)sPE;

    int gw = blockIdx.x * 16 + (tid >> 6);   // 512 blocks * 16 waves = 8192 waves
    int row0 = gw * 32;                      // 32 rows per wave, 8 iters x 4 rows

    float xv[4];
#pragma unroll
    for (int u = 0; u < 4; ++u) xv[u] = x[(row0 + u) * 64 + lane];

#pragma unroll 1
    for (int it = 0; it < 8; ++it) {
        int rowbase = row0 + it * 4;

        float xn[4];
        int nb = (it < 7) ? (rowbase + 4) : rowbase;
#pragma unroll
        for (int u = 0; u < 4; ++u) xn[u] = x[(nb + u) * 64 + lane];

        // ---- unary coarse: range 16 ----
        int t[4];
#pragma unroll
        for (int u = 0; u < 4; ++u) {
            int tt = 0;
#pragma unroll
            for (int j = 0; j < 15; ++j) tt += (xv[u] >= cu[j]);
            t[u] = tt;
        }
        // ---- unary mids: 3 swizzled b32 per row ----
        float ma[4][3];
#pragma unroll
        for (int u = 0; u < 4; ++u) {
            int tb = fbase + ((t[u] << 4) ^ fh);
            ma[u][0] = sE[tb + ci0];
            ma[u][1] = sE[tb + ci1];
            ma[u][2] = sE[tb + ci2];
        }

        // ---- pair coarse (overlaps mid latency) ----
        int t2[4] = {0, 0, 0, 0};
        if (act) {
#pragma unroll
            for (int u = 0; u < 4; ++u) {
                int tt = 0;
#pragma unroll
                for (int j = 0; j < 15; ++j) tt += (xv[u] >= cp[j]);
                t2[u] = tt;
            }
        }

        // ---- unary mid consume -> fine b128 load ----
        int cpart[4];
        float4 fv[4];
#pragma unroll
        for (int u = 0; u < 4; ++u) {
            int m = (xv[u] >= ma[u][0]) + (xv[u] >= ma[u][1]) + (xv[u] >= ma[u][2]);
            cpart[u] = (t[u] << 4) + (m << 2);
            fv[u] = sE4[(lane << 6) + (((t[u] << 2) + m) ^ fq)];
        }

        // ---- pair mids ----
        float mb[4][3];
        if (act) {
#pragma unroll
            for (int u = 0; u < 4; ++u) {
                int tb = fbase + ((t2[u] << 4) ^ fh);
                mb[u][0] = sPE[tb + ci0];
                mb[u][1] = sPE[tb + ci1];
                mb[u][2] = sPE[tb + ci2];
            }
        }

        // ---- unary fine consume (count-all-4, top always 0) -> W gather ----
        float wv[4];
#pragma unroll
        for (int u = 0; u < 4; ++u) {
            int cnt = (xv[u] >= fv[u].x) + (xv[u] >= fv[u].y) +
                      (xv[u] >= fv[u].z) + (xv[u] >= fv[u].w);
            int c = cpart[u] + cnt;          // raw count 0..255; sW pre-shifted
            wv[u] = __half2float(sW[fbase + c]);
        }

        // ---- pair fine ----
        int pidx[4] = {0, 0, 0, 0};
        if (act) {
            float4 gv[4];
#pragma unroll
            for (int u = 0; u < 4; ++u) {
                int m = (xv[u] >= mb[u][0]) + (xv[u] >= mb[u][1]) + (xv[u] >= mb[u][2]);
                pidx[u] = (t2[u] << 4) + (m << 2);
                gv[u] = sPE4[(lane << 6) + (((t2[u] << 2) + m) ^ fq)];
            }
#pragma unroll
            for (int u = 0; u < 4; ++u) {
                pidx[u] += (xv[u] >= gv[u].x) + (xv[u] >= gv[u].y) +
                           (xv[u] >= gv[u].z) + (xv[u] >= gv[u].w);
            }
        }

        // ---- packed exchange (4 rows, 8-bit counts) + table gather ----
        int pk = pidx[0] | (pidx[1] << 8) | (pidx[2] << 16) | (pidx[3] << 24);
        int lk = __shfl(pk, pa, 64);
        int rk = __shfl(pk, pb, 64);
        float tv[4] = {0.f, 0.f, 0.f, 0.f};
        if (lane < NPAIRS) {
            if (useT16) {
#pragma unroll
                for (int u = 0; u < 4; ++u) {
                    int li = (lk >> (8 * u)) & 255;
                    int ri = (rk >> (8 * u)) & 255;
                    tv[u] = __half2float(T16[(lane << 16) + (li << 8) + ri]);
                }
            } else {
#pragma unroll
                for (int u = 0; u < 4; ++u) {
                    int li = (lk >> (8 * u)) & 255;
                    int ri = (rk >> (8 * u)) & 255;
                    int lb = (li < 255) ? li + 1 : 0;
                    int rb = (ri < 255) ? ri + 1 : 0;
                    tv[u] = tables_f32[(lane << 16) + (lb << 8) + rb];
                }
            }
        }

        // ---- 4-row reduction: 7 shuffles ----
        float s0 = wv[0] + tv[0];
        float s1 = wv[1] + tv[1];
        float s2 = wv[2] + tv[2];
        float s3 = wv[3] + tv[3];
        float m01 = merge2(s0, s1, 1, lane);
        float m23 = merge2(s2, s3, 1, lane);
        float q   = merge2(m01, m23, 2, lane);
#pragma unroll
        for (int o = 4; o <= 32; o <<= 1) q += __shfl_xor(q, o, 64);

        if (lane < 4) {
            out[rowbase + lane] = 1.0f / (1.0f + __expf(-(q + bias0)));
        }

        xv[0] = xn[0]; xv[1] = xn[1]; xv[2] = xn[2]; xv[3] = xn[3];
    }
}

extern "C" void kernel_launch(void* const* d_in, const int* in_sizes, int n_in,
                              void* d_out, int out_size, void* d_ws, size_t ws_size,
                              hipStream_t stream) {
    const float* x          = (const float*)d_in[0];
    const float* edges      = (const float*)d_in[1];
    const float* w          = (const float*)d_in[2];
    const float* pair_edges = (const float*)d_in[3];
    const int*   pairs      = (const int*)d_in[4];
    const float* tables     = (const float*)d_in[5];
    const float* bias       = (const float*)d_in[6];
    float* out = (float*)d_out;
    float* ws  = (float*)d_ws;

    int useT16 = (ws_size >= (size_t)4358144) ? 1 : 0;
    __half* T16 = (__half*)((char*)d_ws + 163840);

    ebm_prep_edges<<<64, 256, 0, stream>>>(edges, pair_edges, w, ws);
    if (useT16) {
        ebm_prep_tables<<<2048, 1024, 0, stream>>>(tables, (unsigned short*)T16);
    }
    ebm_main<<<512, 1024, 0, stream>>>(x, pairs, tables, bias, ws, T16, useT16, out);
}